// Round 7
// baseline (399.541 us; speedup 1.0000x reference)
//
#include <hip/hip_runtime.h>
#include <math.h>

#define N 512
#define CS 384
#define CZ 128
#define NH 16
#define DH 24
#define HD 384
#define NN (N*N)
#define EPS 1e-5f

// ws layout (float offsets)
#define OFF_AN   0          // a_n [N][CS]
#define OFF_QT   196608     // qT [H][N][D] (pre-scaled by 1/sqrt(24))
#define OFF_KT   393216     // kT [H][N][D]
#define OFF_VT   589824     // vT [H][N][D]
#define OFF_GT   786432     // gT [H][N][D] (sigmoid applied)
#define OFF_OG   983040     // o*g [N][HD]
#define OFF_WZ2  1179648    // g_z*Wz transposed [H][CZ]
#define OFF_SH   1181696    // [H]
#define OFF_BH   1181712    // [H]
#define OFF_BIAS 1181728    // pair bias [H][N][N]

// ---------------- fused: prep (block 256) + LayerNorm of a (blocks 0..255, 2 rows each) ----------------
__global__ void __launch_bounds__(256) ln_prep_kernel(const float* __restrict__ a, const float* __restrict__ g_a,
                                                      const float* __restrict__ b_a, float* __restrict__ an_out,
                                                      const float* __restrict__ g_z, const float* __restrict__ lnb_z,
                                                      const float* __restrict__ Wz, const float* __restrict__ bz,
                                                      float* __restrict__ wz2, float* __restrict__ sh,
                                                      float* __restrict__ bh) {
    __shared__ float ls[NH][17], lb[NH][17];   // prep block
    __shared__ float l1[4], l2[4];             // ln blocks
    const int t = threadIdx.x;
    if (blockIdx.x == 256) {
        for (int i = t; i < NH * CZ; i += 256) {
            int h = i >> 7, c = i & (CZ - 1);
            wz2[h * CZ + c] = g_z[c] * Wz[c * NH + h];
        }
        int h = t >> 4, seg = t & 15;
        float s = 0.f, b = 0.f;
        #pragma unroll
        for (int i = 0; i < 8; ++i) {
            int c = seg * 8 + i;
            float w = Wz[c * NH + h];
            s += g_z[c] * w;
            b += lnb_z[c] * w;
        }
        ls[h][seg] = s; lb[h][seg] = b;
        __syncthreads();
        if (t < NH) {
            float ss = 0.f, bb = 0.f;
            #pragma unroll
            for (int i = 0; i < 16; ++i) { ss += ls[t][i]; bb += lb[t][i]; }
            sh[t] = ss;
            bh[t] = bb + bz[t];
        }
        return;
    }
    const int half = t >> 7;
    const int tr = t & 127;
    const int r = blockIdx.x * 2 + half;
    const float* row = a + r * CS;
    float x0 = row[tr], x1 = row[tr + 128], x2 = row[tr + 256];
    float s1 = x0 + x1 + x2;
    float s2 = x0 * x0 + x1 * x1 + x2 * x2;
    #pragma unroll
    for (int m = 1; m < 64; m <<= 1) {
        s1 += __shfl_xor(s1, m, 64);
        s2 += __shfl_xor(s2, m, 64);
    }
    if ((t & 63) == 0) { l1[t >> 6] = s1; l2[t >> 6] = s2; }
    __syncthreads();
    s1 = l1[half * 2] + l1[half * 2 + 1];
    s2 = l2[half * 2] + l2[half * 2 + 1];
    float mu = s1 * (1.f / CS);
    float var = s2 * (1.f / CS) - mu * mu;
    float rs = rsqrtf(var + EPS);
    float* an = an_out + r * CS;
    an[tr]       = (x0 - mu) * rs * g_a[tr]       + b_a[tr];
    an[tr + 128] = (x1 - mu) * rs * g_a[tr + 128] + b_a[tr + 128];
    an[tr + 256] = (x2 - mu) * rs * g_a[tr + 256] + b_a[tr + 256];
}

// ---------------- qkvg v3: LDS-staged an-tile, 4 cols/thread, 3072 waves (R6, neutral-kept) ----------------
__global__ void __launch_bounds__(256) qkvg_kernel(const float* __restrict__ Wq, const float* __restrict__ Wk,
                                                   const float* __restrict__ Wv, const float* __restrict__ Wg,
                                                   const float* __restrict__ bg, const float* __restrict__ an,
                                                   float* __restrict__ qt, float* __restrict__ kt,
                                                   float* __restrict__ vt, float* __restrict__ gt) {
    __shared__ float4 lan[64 * 8];   // 8 KB
    const int t = threadIdx.x;
    const int lane = t & 63;
    const int w = __builtin_amdgcn_readfirstlane(t >> 6);
    const int s = blockIdx.x * 4 + w;     // 0..383 strips
    const int n0 = s * 4;
    const int sel = n0 / HD;              // 0:q 1:k 2:v 3:g
    const int col = n0 - sel * HD;
    const float* Wm = (sel == 0) ? Wq : (sel == 1) ? Wk : (sel == 2) ? Wv : Wg;
    const int m0 = blockIdx.y * 64;
    const int m = m0 + lane;
    const float4* an4 = (const float4*)an;
    float acc[4];
    #pragma unroll
    for (int j = 0; j < 4; ++j) acc[j] = 0.f;
    for (int kb = 0; kb < CS; kb += 32) {
        __syncthreads();
        #pragma unroll
        for (int i = 0; i < 2; ++i) {
            const int idx = i * 256 + t;          // 0..511
            const int r = idx >> 3, c = idx & 7;
            lan[(r << 3) + (c ^ (r & 7))] = an4[(size_t)(m0 + r) * 96 + (kb >> 2) + c];
        }
        __syncthreads();
        float4 av[8];
        #pragma unroll
        for (int i = 0; i < 8; ++i) av[i] = lan[(lane << 3) + (i ^ (lane & 7))];
        #pragma unroll
        for (int i = 0; i < 8; ++i) {
            const float* wr = Wm + (kb + i * 4) * HD + col; // wave-uniform -> s_load
            #pragma unroll
            for (int j = 0; j < 4; ++j) {
                acc[j] += av[i].x * wr[j];
                acc[j] += av[i].y * wr[HD + j];
                acc[j] += av[i].z * wr[2 * HD + j];
                acc[j] += av[i].w * wr[3 * HD + j];
            }
        }
    }
    float* dst = (sel == 0) ? qt : (sel == 1) ? kt : (sel == 2) ? vt : gt;
    if (sel == 3) {
        #pragma unroll
        for (int j = 0; j < 4; ++j) acc[j] = 1.f / (1.f + __expf(-(acc[j] + bg[col + j])));
    } else if (sel == 0) {
        #pragma unroll
        for (int j = 0; j < 4; ++j) acc[j] *= 0.20412414523193153f; // 1/sqrt(24)
    }
    const int h = col / DH, d0 = col - h * DH;
    float* dp = dst + (h * N + m) * DH + d0;
    #pragma unroll
    for (int j = 0; j < 4; ++j) dp[j] = acc[j];
}

// ---------------- pair bias v5: 256-row block, 4x64-row sub-tiles, double-buffered async staging ----------------
// v4's proven compute (4 thr/row, 4 heads, cheap-XOR conflict-free LDS reads) wrapped in a
// 2-deep pipeline: regs(s+1) loaded BEFORE compute(s) (HBM latency hides under VALU), ds_write
// lands after, one barrier per sub-tile. LDS 2x32KB -> 2 blocks/CU; grid 1024.
__global__ void __launch_bounds__(256, 2) pairbias_kernel(const float* __restrict__ z,
                                                          const float* __restrict__ wz2,
                                                          const float* __restrict__ sh,
                                                          const float* __restrict__ bh,
                                                          float* __restrict__ bias) {
    __shared__ float4 buf0[64 * 32];   // 32 KB
    __shared__ float4 buf1[64 * 32];   // 32 KB
    const int t = threadIdx.x;
    const int l = t & 63;                                      // row within sub-tile
    const int w = __builtin_amdgcn_readfirstlane(t >> 6);      // head group (wave-uniform)
    const int h0 = w * 4;
    const int row0 = blockIdx.x * 256;
    const float4* zsrc = (const float4*)z + (size_t)row0 * 32;

#define PB_LOAD(s, rr) { const float4* p_ = zsrc + (s) * 2048; \
    _Pragma("unroll") for (int i = 0; i < 8; ++i) rr[i] = p_[i * 256 + t]; }

#define PB_WRITE(rr, bufp) { _Pragma("unroll") for (int i = 0; i < 8; ++i) { \
    const int g4_ = i * 256 + t; const int r_ = g4_ >> 5, cc_ = g4_ & 31; \
    bufp[r_ * 32 + (cc_ ^ (r_ & 31))] = rr[i]; } }

#define PB_COMPUTE(s, bufp) { \
    const char* lzb_ = (const char*)bufp; \
    const unsigned base_ = (unsigned)(l * 512 + ((l & 31) << 4)); \
    float s1_ = 0.f, s2_ = 0.f, d0_ = 0.f, d1_ = 0.f, d2_ = 0.f, d3_ = 0.f; \
    _Pragma("unroll") for (int cc = 0; cc < 32; ++cc) { \
        float4 v_ = *(const float4*)(lzb_ + (base_ ^ (unsigned)(cc << 4))); \
        s1_ += v_.x + v_.y + v_.z + v_.w; \
        s2_ += v_.x * v_.x + v_.y * v_.y + v_.z * v_.z + v_.w * v_.w; \
        const float4 w0_ = ((const float4*)(wz2 + (h0 + 0) * CZ))[cc]; \
        const float4 w1_ = ((const float4*)(wz2 + (h0 + 1) * CZ))[cc]; \
        const float4 w2_ = ((const float4*)(wz2 + (h0 + 2) * CZ))[cc]; \
        const float4 w3_ = ((const float4*)(wz2 + (h0 + 3) * CZ))[cc]; \
        d0_ += v_.x * w0_.x + v_.y * w0_.y + v_.z * w0_.z + v_.w * w0_.w; \
        d1_ += v_.x * w1_.x + v_.y * w1_.y + v_.z * w1_.z + v_.w * w1_.w; \
        d2_ += v_.x * w2_.x + v_.y * w2_.y + v_.z * w2_.z + v_.w * w2_.w; \
        d3_ += v_.x * w3_.x + v_.y * w3_.y + v_.z * w3_.z + v_.w * w3_.w; } \
    const float mu_ = s1_ * (1.f / CZ); \
    const float var_ = s2_ * (1.f / CZ) - mu_ * mu_; \
    const float rs_ = rsqrtf(var_ + EPS); \
    const int row_ = row0 + (s) * 64 + l; \
    bias[(h0 + 0) * NN + row_] = rs_ * (d0_ - mu_ * sh[h0 + 0]) + bh[h0 + 0]; \
    bias[(h0 + 1) * NN + row_] = rs_ * (d1_ - mu_ * sh[h0 + 1]) + bh[h0 + 1]; \
    bias[(h0 + 2) * NN + row_] = rs_ * (d2_ - mu_ * sh[h0 + 2]) + bh[h0 + 2]; \
    bias[(h0 + 3) * NN + row_] = rs_ * (d3_ - mu_ * sh[h0 + 3]) + bh[h0 + 3]; }

    float4 ra[8], rb[8];
    PB_LOAD(0, ra); PB_WRITE(ra, buf0); __syncthreads();
    PB_LOAD(1, rb);                 // in flight during compute(0)
    PB_COMPUTE(0, buf0);
    PB_WRITE(rb, buf1); __syncthreads();
    PB_LOAD(2, ra);                 // in flight during compute(1)
    PB_COMPUTE(1, buf1);
    PB_WRITE(ra, buf0); __syncthreads();
    PB_LOAD(3, rb);                 // in flight during compute(2)
    PB_COMPUTE(2, buf0);
    PB_WRITE(rb, buf1); __syncthreads();
    PB_COMPUTE(3, buf1);
#undef PB_LOAD
#undef PB_WRITE
#undef PB_COMPUTE
}

// ---------------- attn v2: flash-style with LDS-staged K/V tiles (R6, neutral-kept) ----------------
__global__ void __launch_bounds__(256, 4) attn_kernel(const float* __restrict__ qt, const float* __restrict__ kt,
                                                      const float* __restrict__ vt, const float* __restrict__ gt,
                                                      const float* __restrict__ bias, float* __restrict__ og) {
    __shared__ float4 lzK[128 * 8];   // 16 KB
    __shared__ float4 lzV[128 * 8];   // 16 KB
    const int t = threadIdx.x;
    const int lane = t & 63;
    const int w = __builtin_amdgcn_readfirstlane(t >> 6);
    const int qhalf = lane >> 5;     // 0/1
    const int klane = lane & 31;
    const int h = blockIdx.y;
    const int q = blockIdx.x * 8 + w * 2 + qhalf;
    const float* qT = qt + h * N * DH;
    const float4* kT4 = (const float4*)(kt + h * N * DH);
    const float4* vT4 = (const float4*)(vt + h * N * DH);
    const float* brow = bias + h * NN + q * N;

    float qv[DH];
    #pragma unroll
    for (int d6 = 0; d6 < 6; ++d6) {
        float4 t4 = ((const float4*)(qT + q * DH))[d6];
        qv[d6 * 4 + 0] = t4.x; qv[d6 * 4 + 1] = t4.y; qv[d6 * 4 + 2] = t4.z; qv[d6 * 4 + 3] = t4.w;
    }
    float m_run = -1e30f, l_run = 0.f;
    float acc[DH];
    #pragma unroll
    for (int d = 0; d < DH; ++d) acc[d] = 0.f;

    for (int tile = 0; tile < 4; ++tile) {
        __syncthreads();
        const int kt0 = tile * 128;
        #pragma unroll
        for (int i = 0; i < 3; ++i) {
            const int idx = i * 256 + t;       // 0..767 (= r*6+c, rows contiguous)
            const int r = idx / 6, c = idx - r * 6;
            const int slot = (r << 3) + (c ^ (r & 7));
            lzK[slot] = kT4[kt0 * 6 + idx];
            lzV[slot] = vT4[kt0 * 6 + idx];
        }
        __syncthreads();
        float sc[4];
        #pragma unroll
        for (int j = 0; j < 4; ++j) {
            const int kk = j * 32 + klane;
            const float4* kr = lzK + (kk << 3);
            const int x = kk & 7;
            float4 k0 = kr[0 ^ x], k1 = kr[1 ^ x], k2 = kr[2 ^ x],
                   k3 = kr[3 ^ x], k4 = kr[4 ^ x], k5 = kr[5 ^ x];
            float s = qv[0]*k0.x + qv[1]*k0.y + qv[2]*k0.z + qv[3]*k0.w
                    + qv[4]*k1.x + qv[5]*k1.y + qv[6]*k1.z + qv[7]*k1.w
                    + qv[8]*k2.x + qv[9]*k2.y + qv[10]*k2.z + qv[11]*k2.w
                    + qv[12]*k3.x + qv[13]*k3.y + qv[14]*k3.z + qv[15]*k3.w
                    + qv[16]*k4.x + qv[17]*k4.y + qv[18]*k4.z + qv[19]*k4.w
                    + qv[20]*k5.x + qv[21]*k5.y + qv[22]*k5.z + qv[23]*k5.w;
            sc[j] = s + brow[kt0 + kk];
        }
        float tm = fmaxf(fmaxf(sc[0], sc[1]), fmaxf(sc[2], sc[3]));
        #pragma unroll
        for (int m = 1; m < 32; m <<= 1) tm = fmaxf(tm, __shfl_xor(tm, m, 64));
        const float m_new = fmaxf(m_run, tm);
        const float scale = __expf(m_run - m_new);
        l_run *= scale;
        #pragma unroll
        for (int d = 0; d < DH; ++d) acc[d] *= scale;
        float p[4], ps = 0.f;
        #pragma unroll
        for (int j = 0; j < 4; ++j) { p[j] = __expf(sc[j] - m_new); ps += p[j]; }
        #pragma unroll
        for (int m = 1; m < 32; m <<= 1) ps += __shfl_xor(ps, m, 64);
        l_run += ps;
        m_run = m_new;
        #pragma unroll
        for (int j = 0; j < 4; ++j) {
            const int kk = j * 32 + klane;
            const float4* vr = lzV + (kk << 3);
            const int x = kk & 7;
            float4 v0 = vr[0 ^ x], v1 = vr[1 ^ x], v2 = vr[2 ^ x],
                   v3 = vr[3 ^ x], v4 = vr[4 ^ x], v5 = vr[5 ^ x];
            const float pj = p[j];
            acc[0] += pj*v0.x;  acc[1] += pj*v0.y;  acc[2] += pj*v0.z;  acc[3] += pj*v0.w;
            acc[4] += pj*v1.x;  acc[5] += pj*v1.y;  acc[6] += pj*v1.z;  acc[7] += pj*v1.w;
            acc[8] += pj*v2.x;  acc[9] += pj*v2.y;  acc[10] += pj*v2.z; acc[11] += pj*v2.w;
            acc[12] += pj*v3.x; acc[13] += pj*v3.y; acc[14] += pj*v3.z; acc[15] += pj*v3.w;
            acc[16] += pj*v4.x; acc[17] += pj*v4.y; acc[18] += pj*v4.z; acc[19] += pj*v4.w;
            acc[20] += pj*v5.x; acc[21] += pj*v5.y; acc[22] += pj*v5.z; acc[23] += pj*v5.w;
        }
    }
    #pragma unroll
    for (int m = 1; m < 32; m <<= 1) {
        #pragma unroll
        for (int d = 0; d < DH; ++d) acc[d] += __shfl_xor(acc[d], m, 64);
    }
    const float inv = 1.f / l_run;
    float o = 0.f;
    #pragma unroll
    for (int d = 0; d < DH; ++d) o = (klane == d) ? acc[d] : o;
    if (klane < DH) {
        float g = gt[h * N * DH + q * DH + klane];
        og[q * HD + h * DH + klane] = o * inv * g;
    }
}

// ---------------- out_gemm v3: LDS-staged og-tile, 2 cols/thread, 1536 waves (R6, neutral-kept) ----------------
__global__ void __launch_bounds__(256) out_gemm_kernel(const float* __restrict__ Wo, const float* __restrict__ bo,
                                                       const float* __restrict__ og, float* __restrict__ out) {
    __shared__ float4 lo[64 * 8];    // 8 KB
    const int t = threadIdx.x;
    const int lane = t & 63;
    const int w = __builtin_amdgcn_readfirstlane(t >> 6);
    const int s = blockIdx.x * 4 + w;     // 0..191 strips of 2 cols
    const int c0 = s * 2;
    const int m0 = blockIdx.y * 64;
    const int m = m0 + lane;
    const float4* og4 = (const float4*)og;
    float acc[2];
    acc[0] = 0.f; acc[1] = 0.f;
    for (int kb = 0; kb < HD; kb += 32) {
        __syncthreads();
        #pragma unroll
        for (int i = 0; i < 2; ++i) {
            const int idx = i * 256 + t;          // 0..511
            const int r = idx >> 3, c = idx & 7;
            lo[(r << 3) + (c ^ (r & 7))] = og4[(size_t)(m0 + r) * 96 + (kb >> 2) + c];
        }
        __syncthreads();
        float4 av[8];
        #pragma unroll
        for (int i = 0; i < 8; ++i) av[i] = lo[(lane << 3) + (i ^ (lane & 7))];
        #pragma unroll
        for (int i = 0; i < 8; ++i) {
            const float* wr = Wo + (kb + i * 4) * CS + c0; // uniform -> s_load
            #pragma unroll
            for (int j = 0; j < 2; ++j) {
                acc[j] += av[i].x * wr[j];
                acc[j] += av[i].y * wr[CS + j];
                acc[j] += av[i].z * wr[2 * CS + j];
                acc[j] += av[i].w * wr[3 * CS + j];
            }
        }
    }
    #pragma unroll
    for (int j = 0; j < 2; ++j) out[m * CS + c0 + j] = acc[j] + bo[c0 + j];
}

extern "C" void kernel_launch(void* const* d_in, const int* in_sizes, int n_in,
                              void* d_out, int out_size, void* d_ws, size_t ws_size,
                              hipStream_t stream) {
    const float* a    = (const float*)d_in[0];
    const float* z    = (const float*)d_in[1];
    const float* g_a  = (const float*)d_in[2];
    const float* b_a  = (const float*)d_in[3];
    const float* g_z  = (const float*)d_in[4];
    const float* b_z  = (const float*)d_in[5];
    const float* Wz   = (const float*)d_in[6];
    const float* bz   = (const float*)d_in[7];
    const float* Wq   = (const float*)d_in[8];
    const float* Wk   = (const float*)d_in[9];
    const float* Wv   = (const float*)d_in[10];
    const float* Wg   = (const float*)d_in[11];
    const float* bg   = (const float*)d_in[12];
    const float* Wo   = (const float*)d_in[13];
    const float* bo   = (const float*)d_in[14];
    float* ws  = (float*)d_ws;
    float* out = (float*)d_out;

    float* an   = ws + OFF_AN;
    float* qt   = ws + OFF_QT;
    float* kt   = ws + OFF_KT;
    float* vt   = ws + OFF_VT;
    float* gt   = ws + OFF_GT;
    float* ogp  = ws + OFF_OG;
    float* wz2  = ws + OFF_WZ2;
    float* shp  = ws + OFF_SH;
    float* bhp  = ws + OFF_BH;
    float* bias = ws + OFF_BIAS;

    hipLaunchKernelGGL(ln_prep_kernel, dim3(257),    dim3(256), 0, stream,
                       a, g_a, b_a, an, g_z, b_z, Wz, bz, wz2, shp, bhp);
    hipLaunchKernelGGL(qkvg_kernel,    dim3(96, 8),  dim3(256), 0, stream,
                       Wq, Wk, Wv, Wg, bg, an, qt, kt, vt, gt);
    hipLaunchKernelGGL(pairbias_kernel, dim3(1024),  dim3(256), 0, stream,
                       z, wz2, shp, bhp, bias);
    hipLaunchKernelGGL(attn_kernel,    dim3(64, 16), dim3(256), 0, stream,
                       qt, kt, vt, gt, bias, ogp);
    hipLaunchKernelGGL(out_gemm_kernel, dim3(48, 8), dim3(256), 0, stream,
                       Wo, bo, ogp, out);
}